// Round 1
// baseline (299.972 us; speedup 1.0000x reference)
//
#include <hip/hip_runtime.h>
#include <stdint.h>

#define B_   8
#define N_   8192
#define S_   2048
#define D1_  128
#define D2_  256
#define CIN_ 384
#define C1_  256
#define C2_  128

typedef uint16_t u16;
typedef uint32_t u32;
typedef __attribute__((ext_vector_type(8))) short bf16x8;
typedef __attribute__((ext_vector_type(4))) float f32x4;

static __device__ __forceinline__ u16 f2bf(float f){
    union { float f; u32 u; } v; v.f = f;
    u32 r = v.u + 0x7FFF + ((v.u >> 16) & 1);
    return (u16)(r >> 16);
}
static __device__ __forceinline__ float bf2f(u16 h){
    union { u32 u; float f; } v; v.u = ((u32)h) << 16;
    return v.f;
}
static __device__ __forceinline__ uint4 pack8(const u16 h[8]){
    uint4 u;
    u.x = (u32)h[0] | ((u32)h[1] << 16);
    u.y = (u32)h[2] | ((u32)h[3] << 16);
    u.z = (u32)h[4] | ((u32)h[5] << 16);
    u.w = (u32)h[6] | ((u32)h[7] << 16);
    return u;
}
#define EXT8(dst, u) { dst[0]=bf2f((u16)(u).x); dst[1]=bf2f((u16)((u).x>>16)); \
                       dst[2]=bf2f((u16)(u).y); dst[3]=bf2f((u16)((u).y>>16)); \
                       dst[4]=bf2f((u16)(u).z); dst[5]=bf2f((u16)((u).z>>16)); \
                       dst[6]=bf2f((u16)(u).w); dst[7]=bf2f((u16)((u).w>>16)); }

// ---------------- prep: weights -> bf16 ----------------
__global__ void k_prep_w(const float* __restrict__ w1, const float* __restrict__ w2,
                         u16* __restrict__ w1bf, u16* __restrict__ w2bf){
    int i = blockIdx.x * 256 + threadIdx.x;
    if (i < C1_*CIN_) w1bf[i] = f2bf(w1[i]);
    if (i < C2_*C1_)  w2bf[i] = f2bf(w2[i]);
}

// ---------------- prep: points2 [b][d][s] -> p2t bf16 [b][s][d] ----------------
__global__ __launch_bounds__(256) void k_p2t(const float* __restrict__ p2, u16* __restrict__ p2t){
    // grid (S/32, D2/32, B)
    __shared__ float t[32][33];
    int b = blockIdx.z, s0 = blockIdx.x * 32, d0 = blockIdx.y * 32;
    int tt = threadIdx.x;
    int r = tt >> 3, c4 = (tt & 7) * 4;
    const float* src = p2 + (((size_t)b*D2_ + d0 + r) * S_ + s0 + c4);
    float4 v = *(const float4*)src;
    t[r][c4+0]=v.x; t[r][c4+1]=v.y; t[r][c4+2]=v.z; t[r][c4+3]=v.w;
    __syncthreads();
    ushort4 o;
    o.x = f2bf(t[c4+0][r]); o.y = f2bf(t[c4+1][r]);
    o.z = f2bf(t[c4+2][r]); o.w = f2bf(t[c4+3][r]);
    u16* dst = p2t + (((size_t)b*S_ + s0 + r) * D2_ + d0 + c4);
    *(ushort4*)dst = o;
}

// ---------------- 3-NN search ----------------
#define INS3(dd, ss) do{ if ((dd) < d2){ if ((dd) < d1){ d2=d1; i2=i1; \
    if ((dd) < d0){ d1=d0; i1=i0; d0=(dd); i0=(ss); } else { d1=(dd); i1=(ss); } } \
    else { d2=(dd); i2=(ss); } } }while(0)

__global__ __launch_bounds__(256) void k_nn(const float* __restrict__ xyz1,
                                            const float* __restrict__ xyz2,
                                            int* __restrict__ nn_idx, float* __restrict__ nn_w){
    // grid (N/128, B); 2 threads per query point, each scans half of S
    __shared__ float4 pt[S_];
    int b = blockIdx.y;
    int t = threadIdx.x;
    const float* xb = xyz2 + (size_t)b*3*S_;
    for (int i = t; i < S_; i += 256){
        float x = xb[i], y = xb[S_ + i], z = xb[2*S_ + i];
        pt[i] = make_float4(x, y, z, x*x + y*y + z*z);
    }
    __syncthreads();
    int nl = t >> 1, half = t & 1;
    int n = blockIdx.x * 128 + nl;
    const float* x1b = xyz1 + (size_t)b*3*N_;
    float px = x1b[n], py = x1b[N_ + n], pz = x1b[2*N_ + n];
    float n1 = px*px + py*py + pz*pz;
    float d0 = 3.4e38f, d1 = 3.4e38f, d2 = 3.4e38f;
    int i0 = 0, i1 = 0, i2 = 0;
    int sbeg = half * (S_/2), send = sbeg + (S_/2);
    #pragma unroll 4
    for (int s = sbeg; s < send; ++s){
        float4 q = pt[s];
        float dot = fmaf(px, q.x, fmaf(py, q.y, pz*q.z));
        float d = fmaf(-2.f, dot, n1 + q.w);
        INS3(d, s);
    }
    // merge with partner lane (other half of S). Partner of half==0 has larger
    // indices, so strict < keeps correct lowest-index tie-break for half==0.
    float e0=__shfl_xor(d0,1), e1=__shfl_xor(d1,1), e2=__shfl_xor(d2,1);
    int   j0=__shfl_xor(i0,1), j1=__shfl_xor(i1,1), j2=__shfl_xor(i2,1);
    INS3(e0, j0); INS3(e1, j1); INS3(e2, j2);
    if (half == 0){
        float r0 = 1.f/(d0+1e-8f), r1 = 1.f/(d1+1e-8f), r2 = 1.f/(d2+1e-8f);
        float inv = 1.f/(r0+r1+r2);
        size_t base = ((size_t)b*N_ + n)*3;
        nn_idx[base]=i0; nn_idx[base+1]=i1; nn_idx[base+2]=i2;
        nn_w[base]=r0*inv; nn_w[base+1]=r1*inv; nn_w[base+2]=r2*inv;
    }
}

// ---------------- conv1: build X-tile (concat) in LDS, MFMA, BN1 partials, y1 bf16 out ----------------
// LDS Xt layout: 64 rows (n), 768B per row (384 bf16), XOR-swizzled.
#define SWZ(nrow, kbyte) ((((nrow)*768 + (kbyte))) ^ (((nrow)&7)<<4))
#define SWZ2(nrow, kbyte) ((((nrow)*512 + (kbyte))) ^ (((nrow)&7)<<4))

__global__ __launch_bounds__(256) void k_conv1(const u16* __restrict__ w1bf,
    const float* __restrict__ b1, const float* __restrict__ points1,
    const u16* __restrict__ p2t, const int* __restrict__ nn_idx,
    const float* __restrict__ nn_w, u16* __restrict__ y1, float* __restrict__ part1){
    __shared__ char sm[48*1024 + 8*1024];
    char* Xt = sm;                               // 48KB build tile; reused as 32KB y1 stage
    float* st = (float*)(sm + 48*1024);          // [2][4 waves][256 ch]
    int b = blockIdx.y, n0 = blockIdx.x * 64;
    int t = threadIdx.x;

    // ---- phase A: points1 channels 0..127
    {
        int n = t >> 2, kc = (t & 3) * 32;
        const float* src = points1 + ((size_t)b*D1_ + kc)*N_ + n0 + n;
        #pragma unroll
        for (int c = 0; c < 4; ++c){
            u16 h[8];
            #pragma unroll
            for (int j = 0; j < 8; ++j) h[j] = f2bf(src[(size_t)(c*8 + j)*N_]);
            *(uint4*)(Xt + SWZ(n, (kc + c*8)*2)) = pack8(h);
        }
    }
    // ---- phase B: interpolated points2 channels 128..383
    {
        int n = t >> 2, cc = (t & 3) * 64;
        size_t nb = ((size_t)b*N_ + n0 + n)*3;
        int ia = nn_idx[nb], ib = nn_idx[nb+1], ic = nn_idx[nb+2];
        float wa = nn_w[nb], wb = nn_w[nb+1], wc = nn_w[nb+2];
        const u16* ra = p2t + ((size_t)b*S_ + ia)*D2_ + cc;
        const u16* rb = p2t + ((size_t)b*S_ + ib)*D2_ + cc;
        const u16* rc = p2t + ((size_t)b*S_ + ic)*D2_ + cc;
        #pragma unroll
        for (int c = 0; c < 8; ++c){
            uint4 ua = *(const uint4*)(ra + c*8);
            uint4 ub = *(const uint4*)(rb + c*8);
            uint4 uc = *(const uint4*)(rc + c*8);
            float va[8], vb[8], vc[8];
            EXT8(va, ua); EXT8(vb, ub); EXT8(vc, uc);
            u16 h[8];
            #pragma unroll
            for (int e = 0; e < 8; ++e)
                h[e] = f2bf(fmaf(wa, va[e], fmaf(wb, vb[e], wc*vc[e])));
            *(uint4*)(Xt + SWZ(n, (128 + cc + c*8)*2)) = pack8(h);
        }
    }
    __syncthreads();

    // ---- GEMM: M=256 (16 mt), N=64 (wave-split 4x16), K=384 (12 K-steps)
    int lane = t & 63, wave = t >> 6;
    int nrow = wave*16 + (lane & 15);
    int kgrp = (lane >> 4) * 8;
    bf16x8 bfr[12];
    #pragma unroll
    for (int ks = 0; ks < 12; ++ks)
        bfr[ks] = *(const bf16x8*)(Xt + SWZ(nrow, (ks*32 + kgrp)*2));
    __syncthreads();   // Xt registers captured; LDS now reusable as y1 stage
    char* Yt = sm;     // 64 rows * 512B (256 bf16), swizzled

    const u16* wbase = w1bf + (size_t)(lane & 15)*CIN_ + kgrp;
    #pragma unroll 1
    for (int mt = 0; mt < 16; ++mt){
        f32x4 acc = {0.f, 0.f, 0.f, 0.f};
        const u16* wp = wbase + (size_t)mt*16*CIN_;
        #pragma unroll
        for (int ks = 0; ks < 12; ++ks){
            bf16x8 af = *(const bf16x8*)(wp + ks*32);
            acc = __builtin_amdgcn_mfma_f32_16x16x32_bf16(af, bfr[ks], acc, 0, 0, 0);
        }
        int obase = mt*16 + (lane >> 4)*4;
        #pragma unroll
        for (int r = 0; r < 4; ++r){
            int o = obase + r;
            float v = acc[r] + b1[o];
            *(u16*)(Yt + SWZ2(nrow, o*2)) = f2bf(v);
            float s1 = v, s2 = v*v;
            #pragma unroll
            for (int m = 1; m <= 8; m <<= 1){ s1 += __shfl_xor(s1, m); s2 += __shfl_xor(s2, m); }
            if ((lane & 15) == 0){ st[wave*256 + o] = s1; st[1024 + wave*256 + o] = s2; }
        }
    }
    __syncthreads();

    // ---- BN1 partials (deterministic, per block)
    if (t < 256){
        float s1 = st[t] + st[256+t] + st[512+t] + st[768+t];
        float s2 = st[1024+t] + st[1280+t] + st[1536+t] + st[1792+t];
        int blk = blockIdx.y * gridDim.x + blockIdx.x;
        part1[(size_t)blk*C1_ + t] = s1;
        part1[(size_t)1024*C1_ + (size_t)blk*C1_ + t] = s2;
    }
    // ---- y1 copy-out, coalesced (row n = 512B = 32 x 16B chunks)
    size_t ybase = ((size_t)b*N_ + n0) * C1_;
    #pragma unroll
    for (int jj = 0; jj < 8; ++jj){
        int id = jj*256 + t;
        int n = id >> 5, ko = id & 31;
        uint4 v = *(const uint4*)(Yt + ((n*512 + ko*16) ^ ((n&7)<<4)));
        *(uint4*)(y1 + ybase + (size_t)n*C1_ + ko*8) = v;
    }
}

// ---------------- conv2: z = relu(bn1(y1)) on the fly, MFMA, BN2 partials, pre-BN out ----------------
__global__ __launch_bounds__(256) void k_conv2(const u16* __restrict__ w2bf,
    const float* __restrict__ b2, const u16* __restrict__ y1,
    const float* __restrict__ a1c1, float* __restrict__ out, float* __restrict__ part2){
    __shared__ char sm[32*1024];          // Zt: 64 rows * 512B, swizzled
    __shared__ float st[2*4*C2_];
    __shared__ float la[C1_], lc[C1_];
    int b = blockIdx.y, n0 = blockIdx.x * 64;
    int t = threadIdx.x;
    if (t < 256){ la[t] = a1c1[t]; lc[t] = a1c1[256 + t]; }
    __syncthreads();
    // build Zt
    {
        int n = t >> 2, kc = (t & 3) * 64;
        const u16* src = y1 + ((size_t)b*N_ + n0 + n)*C1_ + kc;
        #pragma unroll
        for (int c = 0; c < 8; ++c){
            uint4 u = *(const uint4*)(src + c*8);
            float vy[8]; EXT8(vy, u);
            u16 h[8];
            #pragma unroll
            for (int e = 0; e < 8; ++e){
                int k = kc + c*8 + e;
                float z = fmaf(la[k], vy[e], lc[k]);
                h[e] = f2bf(z > 0.f ? z : 0.f);
            }
            *(uint4*)(sm + SWZ2(n, (kc + c*8)*2)) = pack8(h);
        }
    }
    __syncthreads();
    int lane = t & 63, wave = t >> 6;
    int nrow = wave*16 + (lane & 15);
    int kgrp = (lane >> 4) * 8;
    bf16x8 bfr[8];
    #pragma unroll
    for (int ks = 0; ks < 8; ++ks)
        bfr[ks] = *(const bf16x8*)(sm + SWZ2(nrow, (ks*32 + kgrp)*2));
    const u16* wbase = w2bf + (size_t)(lane & 15)*C1_ + kgrp;
    #pragma unroll 1
    for (int mt = 0; mt < 8; ++mt){
        f32x4 acc = {0.f, 0.f, 0.f, 0.f};
        const u16* wp = wbase + (size_t)mt*16*C1_;
        #pragma unroll
        for (int ks = 0; ks < 8; ++ks){
            bf16x8 af = *(const bf16x8*)(wp + ks*32);
            acc = __builtin_amdgcn_mfma_f32_16x16x32_bf16(af, bfr[ks], acc, 0, 0, 0);
        }
        int obase = mt*16 + (lane >> 4)*4;
        #pragma unroll
        for (int r = 0; r < 4; ++r){
            int o = obase + r;
            float v = acc[r] + b2[o];
            out[((size_t)b*C2_ + o)*N_ + n0 + wave*16 + (lane & 15)] = v;
            float s1 = v, s2 = v*v;
            #pragma unroll
            for (int m = 1; m <= 8; m <<= 1){ s1 += __shfl_xor(s1, m); s2 += __shfl_xor(s2, m); }
            if ((lane & 15) == 0){ st[wave*C2_ + o] = s1; st[512 + wave*C2_ + o] = s2; }
        }
    }
    __syncthreads();
    if (t < C2_){
        float s1 = st[t] + st[128+t] + st[256+t] + st[384+t];
        float s2 = st[512+t] + st[640+t] + st[768+t] + st[896+t];
        int blk = blockIdx.y * gridDim.x + blockIdx.x;
        part2[(size_t)blk*C2_ + t] = s1;
        part2[(size_t)1024*C2_ + (size_t)blk*C2_ + t] = s2;
    }
}

// ---------------- finalize BN stats: partials -> a,c per channel ----------------
__global__ void k_finalize(const float* __restrict__ part, int C, int NB, float count,
                           const float* __restrict__ gamma, const float* __restrict__ beta,
                           float* __restrict__ ac){
    int o = blockIdx.x, t = threadIdx.x;
    float s1 = 0.f, s2 = 0.f;
    for (int i = t; i < NB; i += 256){
        s1 += part[(size_t)i*C + o];
        s2 += part[(size_t)NB*C + (size_t)i*C + o];
    }
    #pragma unroll
    for (int m = 1; m < 64; m <<= 1){ s1 += __shfl_xor(s1, m); s2 += __shfl_xor(s2, m); }
    __shared__ float ls[8];
    int wave = t >> 6, lane = t & 63;
    if (lane == 0){ ls[wave] = s1; ls[4+wave] = s2; }
    __syncthreads();
    if (t == 0){
        s1 = ls[0]+ls[1]+ls[2]+ls[3];
        s2 = ls[4]+ls[5]+ls[6]+ls[7];
        float mean = s1 / count;
        float var  = s2 / count - mean*mean;
        float inv  = rsqrtf(var + 1e-5f);
        float a = gamma[o] * inv;
        ac[o] = a;
        ac[C + o] = beta[o] - mean*a;
    }
}

// ---------------- apply BN2 + ReLU in place on d_out ----------------
__global__ void k_apply(float* __restrict__ out, const float* __restrict__ a2c2){
    size_t i4 = (size_t)blockIdx.x * 256 + threadIdx.x;
    float4 v = ((float4*)out)[i4];
    int o = (int)((i4*4 / N_) % C2_);
    float a = a2c2[o], c = a2c2[C2_ + o];
    v.x = fmaxf(fmaf(a, v.x, c), 0.f);
    v.y = fmaxf(fmaf(a, v.y, c), 0.f);
    v.z = fmaxf(fmaf(a, v.z, c), 0.f);
    v.w = fmaxf(fmaf(a, v.w, c), 0.f);
    ((float4*)out)[i4] = v;
}

extern "C" void kernel_launch(void* const* d_in, const int* in_sizes, int n_in,
                              void* d_out, int out_size, void* d_ws, size_t ws_size,
                              hipStream_t stream){
    const float* xyz1    = (const float*)d_in[0];
    const float* xyz2    = (const float*)d_in[1];
    const float* points1 = (const float*)d_in[2];
    const float* points2 = (const float*)d_in[3];
    const float* w1      = (const float*)d_in[4];
    const float* b1      = (const float*)d_in[5];
    const float* gamma1  = (const float*)d_in[6];
    const float* beta1   = (const float*)d_in[7];
    const float* w2      = (const float*)d_in[8];
    const float* b2      = (const float*)d_in[9];
    const float* gamma2  = (const float*)d_in[10];
    const float* beta2   = (const float*)d_in[11];
    float* outp = (float*)d_out;

    char* ws = (char*)d_ws;
    size_t off = 0;
    auto take = [&](size_t sz) -> void* {
        void* p = ws + off;
        off = (off + sz + 255) & ~(size_t)255;
        return p;
    };
    int*   nn_idx = (int*)  take((size_t)B_*N_*3*4);
    float* nn_w   = (float*)take((size_t)B_*N_*3*4);
    u16*   w1bf   = (u16*)  take((size_t)C1_*CIN_*2);
    u16*   w2bf   = (u16*)  take((size_t)C2_*C1_*2);
    u16*   p2t    = (u16*)  take((size_t)B_*S_*D2_*2);
    u16*   y1     = (u16*)  take((size_t)B_*N_*C1_*2);
    float* part1  = (float*)take((size_t)2*1024*C1_*4);
    float* part2  = (float*)take((size_t)2*1024*C2_*4);
    float* a1c1   = (float*)take((size_t)2*C1_*4);
    float* a2c2   = (float*)take((size_t)2*C2_*4);

    hipLaunchKernelGGL(k_prep_w, dim3(384), dim3(256), 0, stream, w1, w2, w1bf, w2bf);
    hipLaunchKernelGGL(k_p2t, dim3(S_/32, D2_/32, B_), dim3(256), 0, stream, points2, p2t);
    hipLaunchKernelGGL(k_nn, dim3(N_/128, B_), dim3(256), 0, stream, xyz1, xyz2, nn_idx, nn_w);
    hipLaunchKernelGGL(k_conv1, dim3(N_/64, B_), dim3(256), 0, stream,
                       w1bf, b1, points1, p2t, nn_idx, nn_w, y1, part1);
    hipLaunchKernelGGL(k_finalize, dim3(C1_), dim3(256), 0, stream,
                       part1, C1_, 1024, (float)(B_*N_), gamma1, beta1, a1c1);
    hipLaunchKernelGGL(k_conv2, dim3(N_/64, B_), dim3(256), 0, stream,
                       w2bf, b2, y1, a1c1, outp, part2);
    hipLaunchKernelGGL(k_finalize, dim3(C2_), dim3(256), 0, stream,
                       part2, C2_, 1024, (float)(B_*N_), gamma2, beta2, a2c2);
    hipLaunchKernelGGL(k_apply, dim3((B_*C2_*N_/4)/256), dim3(256), 0, stream, outp, a2c2);
    (void)in_sizes; (void)n_in; (void)out_size; (void)ws_size;
}

// Round 2
// 265.574 us; speedup vs baseline: 1.1295x; 1.1295x over previous
//
#include <hip/hip_runtime.h>
#include <stdint.h>

#define B_   8
#define N_   8192
#define S_   2048
#define D1_  128
#define D2_  256
#define CIN_ 384
#define C1_  256
#define C2_  128

typedef uint16_t u16;
typedef uint32_t u32;
typedef __attribute__((ext_vector_type(8))) short bf16x8;
typedef __attribute__((ext_vector_type(4))) float f32x4;

static __device__ __forceinline__ u16 f2bf(float f){
    union { float f; u32 u; } v; v.f = f;
    u32 r = v.u + 0x7FFF + ((v.u >> 16) & 1);
    return (u16)(r >> 16);
}
static __device__ __forceinline__ float bf2f(u16 h){
    union { u32 u; float f; } v; v.u = ((u32)h) << 16;
    return v.f;
}
static __device__ __forceinline__ uint4 pack8(const u16 h[8]){
    uint4 u;
    u.x = (u32)h[0] | ((u32)h[1] << 16);
    u.y = (u32)h[2] | ((u32)h[3] << 16);
    u.z = (u32)h[4] | ((u32)h[5] << 16);
    u.w = (u32)h[6] | ((u32)h[7] << 16);
    return u;
}
#define EXT8(dst, u) { dst[0]=bf2f((u16)(u).x); dst[1]=bf2f((u16)((u).x>>16)); \
                       dst[2]=bf2f((u16)(u).y); dst[3]=bf2f((u16)((u).y>>16)); \
                       dst[4]=bf2f((u16)(u).z); dst[5]=bf2f((u16)((u).z>>16)); \
                       dst[6]=bf2f((u16)(u).w); dst[7]=bf2f((u16)((u).w>>16)); }

// ---------------- prep: weights -> bf16 ----------------
__global__ void k_prep_w(const float* __restrict__ w1, const float* __restrict__ w2,
                         u16* __restrict__ w1bf, u16* __restrict__ w2bf){
    int i = blockIdx.x * 256 + threadIdx.x;
    if (i < C1_*CIN_) w1bf[i] = f2bf(w1[i]);
    if (i < C2_*C1_)  w2bf[i] = f2bf(w2[i]);
}

// ---------------- prep: points2 [b][d][s] -> p2t bf16 [b][s][d] ----------------
__global__ __launch_bounds__(256) void k_p2t(const float* __restrict__ p2, u16* __restrict__ p2t){
    __shared__ float t[32][33];
    int b = blockIdx.z, s0 = blockIdx.x * 32, d0 = blockIdx.y * 32;
    int tt = threadIdx.x;
    int r = tt >> 3, c4 = (tt & 7) * 4;
    const float* src = p2 + (((size_t)b*D2_ + d0 + r) * S_ + s0 + c4);
    float4 v = *(const float4*)src;
    t[r][c4+0]=v.x; t[r][c4+1]=v.y; t[r][c4+2]=v.z; t[r][c4+3]=v.w;
    __syncthreads();
    ushort4 o;
    o.x = f2bf(t[c4+0][r]); o.y = f2bf(t[c4+1][r]);
    o.z = f2bf(t[c4+2][r]); o.w = f2bf(t[c4+3][r]);
    u16* dst = p2t + (((size_t)b*S_ + s0 + r) * D2_ + d0 + c4);
    *(ushort4*)dst = o;
}

// ---------------- 3-NN search (dual interleaved chains for ILP) ----------------
#define INS3G(dd, ss, D0,D1,D2,I0,I1,I2) do{ if ((dd) < D2){ if ((dd) < D1){ D2=D1; I2=I1; \
    if ((dd) < D0){ D1=D0; I1=I0; D0=(dd); I0=(ss); } else { D1=(dd); I1=(ss); } } \
    else { D2=(dd); I2=(ss); } } }while(0)

__global__ __launch_bounds__(256) void k_nn(const float* __restrict__ xyz1,
                                            const float* __restrict__ xyz2,
                                            int4* __restrict__ nn_idx4, float4* __restrict__ nn_w4){
    __shared__ float4 pt[S_];
    int b = blockIdx.y;
    int t = threadIdx.x;
    const float* xb = xyz2 + (size_t)b*3*S_;
    for (int i = t; i < S_; i += 256){
        float x = xb[i], y = xb[S_ + i], z = xb[2*S_ + i];
        pt[i] = make_float4(x, y, z, x*x + y*y + z*z);
    }
    __syncthreads();
    int nl = t >> 1, half = t & 1;
    int n = blockIdx.x * 128 + nl;
    const float* x1b = xyz1 + (size_t)b*3*N_;
    float px = x1b[n], py = x1b[N_ + n], pz = x1b[2*N_ + n];
    float n1 = px*px + py*py + pz*pz;
    float a0 = 3.4e38f, a1 = 3.4e38f, a2 = 3.4e38f;
    float b0 = 3.4e38f, b1v = 3.4e38f, b2v = 3.4e38f;
    int ia0 = 0, ia1 = 0, ia2 = 0, ib0 = 0, ib1 = 0, ib2 = 0;
    int sbeg = half * (S_/2), send = sbeg + (S_/2);
    #pragma unroll 4
    for (int s = sbeg; s < send; s += 2){
        float4 qa = pt[s];
        float4 qb = pt[s+1];
        float dota = fmaf(px, qa.x, fmaf(py, qa.y, pz*qa.z));
        float dotb = fmaf(px, qb.x, fmaf(py, qb.y, pz*qb.z));
        float da = fmaf(-2.f, dota, n1 + qa.w);
        float db = fmaf(-2.f, dotb, n1 + qb.w);
        INS3G(da, s,   a0,a1,a2, ia0,ia1,ia2);
        INS3G(db, s+1, b0,b1v,b2v, ib0,ib1,ib2);
    }
    INS3G(b0,  ib0, a0,a1,a2, ia0,ia1,ia2);
    INS3G(b1v, ib1, a0,a1,a2, ia0,ia1,ia2);
    INS3G(b2v, ib2, a0,a1,a2, ia0,ia1,ia2);
    float e0=__shfl_xor(a0,1), e1=__shfl_xor(a1,1), e2=__shfl_xor(a2,1);
    int   j0=__shfl_xor(ia0,1), j1=__shfl_xor(ia1,1), j2=__shfl_xor(ia2,1);
    INS3G(e0, j0, a0,a1,a2, ia0,ia1,ia2);
    INS3G(e1, j1, a0,a1,a2, ia0,ia1,ia2);
    INS3G(e2, j2, a0,a1,a2, ia0,ia1,ia2);
    if (half == 0){
        float r0 = 1.f/(a0+1e-8f), r1 = 1.f/(a1+1e-8f), r2 = 1.f/(a2+1e-8f);
        float inv = 1.f/(r0+r1+r2);
        size_t base = (size_t)b*N_ + n;
        nn_idx4[base] = make_int4(ia0, ia1, ia2, 0);
        nn_w4[base]   = make_float4(r0*inv, r1*inv, r2*inv, 0.f);
    }
}

// LDS swizzles: Xt row=768B, Yt row=512B, Zst row=256B
#define SWZ(nrow, kbyte)  ((((nrow)*768 + (kbyte))) ^ (((nrow)&7)<<4))
#define SWZ2(nrow, kbyte) ((((nrow)*512 + (kbyte))) ^ (((nrow)&7)<<4))
#define SWZ3(nrow, kbyte) ((((nrow)*256 + (kbyte))) ^ (((nrow)&7)<<4))

// ---------------- conv1 ----------------
__global__ __launch_bounds__(256, 2) void k_conv1(const u16* __restrict__ w1bf,
    const float* __restrict__ points1, const u16* __restrict__ p2t,
    const int4* __restrict__ nn_idx4, const float4* __restrict__ nn_w4,
    u16* __restrict__ y1, float* __restrict__ part1){
    __shared__ char sm[48*1024];          // Xt (48K); later Yt(32K)+st(16K)
    char* Xt = sm;
    int b = blockIdx.y, n0 = blockIdx.x * 64;
    int t = threadIdx.x;
    int n = t >> 2, q = t & 3;

    // ---- issue ALL global loads up front (one latency exposure)
    size_t nglob = (size_t)b*N_ + n0 + n;
    int4 nid = nn_idx4[nglob];
    float4 nw = nn_w4[nglob];
    float va[32];
    const float* srcA = points1 + ((size_t)b*D1_ + q*32)*N_ + n0 + n;
    #pragma unroll
    for (int c = 0; c < 4; ++c)
        #pragma unroll
        for (int j = 0; j < 8; ++j) va[c*8+j] = srcA[(size_t)(c*8+j)*N_];
    const u16* ra = p2t + ((size_t)b*S_ + nid.x)*D2_ + q*64;
    const u16* rb = p2t + ((size_t)b*S_ + nid.y)*D2_ + q*64;
    const u16* rc = p2t + ((size_t)b*S_ + nid.z)*D2_ + q*64;
    uint4 ua[8], ub[8], uc[8];
    #pragma unroll
    for (int c = 0; c < 8; ++c){
        ua[c] = *(const uint4*)(ra + c*8);
        ub[c] = *(const uint4*)(rb + c*8);
        uc[c] = *(const uint4*)(rc + c*8);
    }
    // ---- pack + store phase A (ch 0..127)
    #pragma unroll
    for (int c = 0; c < 4; ++c){
        u16 h[8];
        #pragma unroll
        for (int j = 0; j < 8; ++j) h[j] = f2bf(va[c*8+j]);
        *(uint4*)(Xt + SWZ(n, (q*32 + c*8)*2)) = pack8(h);
    }
    // ---- combine + store phase B (ch 128..383)
    #pragma unroll
    for (int c = 0; c < 8; ++c){
        float fa[8], fb[8], fc[8];
        EXT8(fa, ua[c]); EXT8(fb, ub[c]); EXT8(fc, uc[c]);
        u16 h[8];
        #pragma unroll
        for (int e = 0; e < 8; ++e)
            h[e] = f2bf(fmaf(nw.x, fa[e], fmaf(nw.y, fb[e], nw.z*fc[e])));
        *(uint4*)(Xt + SWZ(n, (128 + q*64 + c*8)*2)) = pack8(h);
    }
    __syncthreads();

    // ---- capture X fragments
    int lane = t & 63, wave = t >> 6;
    int nrow = wave*16 + (lane & 15);
    int kgB = (lane >> 4) * 16;
    bf16x8 bfr[12];
    #pragma unroll
    for (int ks = 0; ks < 12; ++ks)
        bfr[ks] = *(const bf16x8*)(Xt + SWZ(nrow, ks*64 + kgB));
    __syncthreads();                      // LDS reusable now
    char* Yt = sm;

    // ---- GEMM with W double-buffer (bias dropped: absorbed by BN mean-sub)
    const u16* wbase = w1bf + (size_t)(lane & 15)*CIN_ + (lane >> 4)*8;
#define LOADW1(buf, mtv) { const u16* wp_ = wbase + (size_t)(mtv)*(16*CIN_); \
    _Pragma("unroll") for (int ks = 0; ks < 12; ++ks) buf[ks] = *(const bf16x8*)(wp_ + ks*32); }
#define MFMA1(buf, mtv) { f32x4 acc = {0.f,0.f,0.f,0.f}; \
    _Pragma("unroll") for (int ks = 0; ks < 12; ++ks) \
        acc = __builtin_amdgcn_mfma_f32_16x16x32_bf16(buf[ks], bfr[ks], acc, 0, 0, 0); \
    int ob_ = (mtv)*16 + (lane >> 4)*4; \
    _Pragma("unroll") for (int r = 0; r < 4; ++r) \
        *(u16*)(Yt + SWZ2(nrow, (ob_ + r)*2)) = f2bf(acc[r]); }
    bf16x8 wA[12], wB[12];
    LOADW1(wA, 0);
    #pragma unroll 1
    for (int mt = 0; mt < 16; mt += 2){
        LOADW1(wB, mt+1);
        MFMA1(wA, mt);
        if (mt + 2 < 16) LOADW1(wA, mt+2);
        MFMA1(wB, mt+1);
    }
    __syncthreads();

    // ---- copy-out y1 + BN1 partial stats from the same reads
    float s1[8] = {0,0,0,0,0,0,0,0}, s2[8] = {0,0,0,0,0,0,0,0};
    int ko = t & 31, rowg = t >> 5;
    size_t ybase = ((size_t)b*N_ + n0) * C1_;
    #pragma unroll
    for (int jj = 0; jj < 8; ++jj){
        int nr = jj*8 + rowg;
        uint4 v = *(const uint4*)(Yt + ((nr*512 + ko*16) ^ ((nr&7)<<4)));
        *(uint4*)(y1 + ybase + (size_t)nr*C1_ + ko*8) = v;
        float f[8]; EXT8(f, v);
        #pragma unroll
        for (int e = 0; e < 8; ++e){ s1[e] += f[e]; s2[e] += f[e]*f[e]; }
    }
    float* st = (float*)(sm + 32*1024);   // [8][256] x2
    #pragma unroll
    for (int e = 0; e < 8; ++e){
        st[rowg*256 + ko*8 + e] = s1[e];
        st[2048 + rowg*256 + ko*8 + e] = s2[e];
    }
    __syncthreads();
    {
        float c1s = 0.f, c2s = 0.f;
        #pragma unroll
        for (int g = 0; g < 8; ++g){ c1s += st[g*256 + t]; c2s += st[2048 + g*256 + t]; }
        int blk = blockIdx.y * gridDim.x + blockIdx.x;
        part1[(size_t)blk*C1_ + t] = c1s;
        part1[(size_t)1024*C1_ + (size_t)blk*C1_ + t] = c2s;
    }
}

// ---------------- conv2: z = relu(bn1(y1)) -> MFMA -> z2 bf16 + BN2 partials ----------------
__global__ __launch_bounds__(256, 2) void k_conv2(const u16* __restrict__ w2bf,
    const u16* __restrict__ y1, const float* __restrict__ a1c1,
    u16* __restrict__ z2bf, float* __restrict__ part2){
    __shared__ char sm[32*1024];          // Zt 32K; later zst(16K)+st(16K)
    __shared__ float la[C1_], lc[C1_];
    int b = blockIdx.y, n0 = blockIdx.x * 64;
    int t = threadIdx.x;
    la[t] = a1c1[t]; lc[t] = a1c1[256 + t];
    // ---- load y1 tile (coalesced: consecutive 16B chunks per instr)
    int n = t >> 2, q = t & 3;
    const u16* src = y1 + ((size_t)b*N_ + n0 + n)*C1_;
    uint4 uy[8];
    #pragma unroll
    for (int c = 0; c < 8; ++c) uy[c] = *(const uint4*)(src + (c*4 + q)*8);
    __syncthreads();   // la/lc ready
    #pragma unroll
    for (int c = 0; c < 8; ++c){
        int k0 = (c*4 + q)*8;
        float vy[8]; EXT8(vy, uy[c]);
        u16 h[8];
        #pragma unroll
        for (int e = 0; e < 8; ++e){
            float z = fmaf(la[k0+e], vy[e], lc[k0+e]);
            h[e] = f2bf(z > 0.f ? z : 0.f);
        }
        *(uint4*)(sm + SWZ2(n, k0*2)) = pack8(h);
    }
    __syncthreads();
    int lane = t & 63, wave = t >> 6;
    int nrow = wave*16 + (lane & 15);
    int kgB = (lane >> 4) * 16;
    bf16x8 bfr[8];
    #pragma unroll
    for (int ks = 0; ks < 8; ++ks)
        bfr[ks] = *(const bf16x8*)(sm + SWZ2(nrow, ks*64 + kgB));
    __syncthreads();                      // LDS reusable
    char* zst = sm;                       // [64][256B] bf16 swizzled

    const u16* wbase = w2bf + (size_t)(lane & 15)*C1_ + (lane >> 4)*8;
#define LOADW2(buf, mtv) { const u16* wp_ = wbase + (size_t)(mtv)*(16*C1_); \
    _Pragma("unroll") for (int ks = 0; ks < 8; ++ks) buf[ks] = *(const bf16x8*)(wp_ + ks*32); }
#define MFMA2(buf, mtv) { f32x4 acc = {0.f,0.f,0.f,0.f}; \
    _Pragma("unroll") for (int ks = 0; ks < 8; ++ks) \
        acc = __builtin_amdgcn_mfma_f32_16x16x32_bf16(buf[ks], bfr[ks], acc, 0, 0, 0); \
    int ob_ = (mtv)*16 + (lane >> 4)*4; \
    _Pragma("unroll") for (int r = 0; r < 4; ++r) \
        *(u16*)(zst + SWZ3(nrow, (ob_ + r)*2)) = f2bf(acc[r]); }
    bf16x8 wA[8], wB[8];
    LOADW2(wA, 0);
    #pragma unroll 1
    for (int mt = 0; mt < 8; mt += 2){
        LOADW2(wB, mt+1);
        MFMA2(wA, mt);
        if (mt + 2 < 8) LOADW2(wA, mt+2);
        MFMA2(wB, mt+1);
    }
    __syncthreads();

    // ---- copy-out z2 bf16 + BN2 partials
    float s1[8] = {0,0,0,0,0,0,0,0}, s2[8] = {0,0,0,0,0,0,0,0};
    int ko = t & 15, rowg = t >> 4;       // 16 chunks/row, 16 row groups of 4
    size_t zbase = ((size_t)b*N_ + n0) * C2_;
    #pragma unroll
    for (int jj = 0; jj < 4; ++jj){
        int nr = jj*16 + rowg;
        uint4 v = *(const uint4*)(zst + ((nr*256 + ko*16) ^ ((nr&7)<<4)));
        *(uint4*)(z2bf + zbase + (size_t)nr*C2_ + ko*8) = v;
        float f[8]; EXT8(f, v);
        #pragma unroll
        for (int e = 0; e < 8; ++e){ s1[e] += f[e]; s2[e] += f[e]*f[e]; }
    }
    float* st = (float*)(sm + 16*1024);   // [16][128] x2
    #pragma unroll
    for (int e = 0; e < 8; ++e){
        st[rowg*128 + ko*8 + e] = s1[e];
        st[2048 + rowg*128 + ko*8 + e] = s2[e];
    }
    __syncthreads();
    if (t < C2_){
        float c1s = 0.f, c2s = 0.f;
        #pragma unroll
        for (int g = 0; g < 16; ++g){ c1s += st[g*128 + t]; c2s += st[2048 + g*128 + t]; }
        int blk = blockIdx.y * gridDim.x + blockIdx.x;
        part2[(size_t)blk*C2_ + t] = c1s;
        part2[(size_t)1024*C2_ + (size_t)blk*C2_ + t] = c2s;
    }
}

// ---------------- finalize BN stats ----------------
__global__ void k_finalize(const float* __restrict__ part, int C, int NB, float count,
                           const float* __restrict__ gamma, const float* __restrict__ beta,
                           float* __restrict__ ac){
    int o = blockIdx.x, t = threadIdx.x;
    float s1 = 0.f, s2 = 0.f;
    for (int i = t; i < NB; i += 256){
        s1 += part[(size_t)i*C + o];
        s2 += part[(size_t)NB*C + (size_t)i*C + o];
    }
    #pragma unroll
    for (int m = 1; m < 64; m <<= 1){ s1 += __shfl_xor(s1, m); s2 += __shfl_xor(s2, m); }
    __shared__ float ls[8];
    int wave = t >> 6, lane = t & 63;
    if (lane == 0){ ls[wave] = s1; ls[4+wave] = s2; }
    __syncthreads();
    if (t == 0){
        s1 = ls[0]+ls[1]+ls[2]+ls[3];
        s2 = ls[4]+ls[5]+ls[6]+ls[7];
        float mean = s1 / count;
        float var  = s2 / count - mean*mean;
        float inv  = rsqrtf(var + 1e-5f);
        float a = gamma[o] * inv;
        ac[o] = a;
        ac[C + o] = beta[o] - mean*a;
    }
}

// ---------------- apply BN2+ReLU with transpose: z2bf [b][n][ch] -> out [b][ch][n] f32 ----------------
__global__ __launch_bounds__(256) void k_apply(const u16* __restrict__ z2bf,
                                               const float* __restrict__ a2c2,
                                               float* __restrict__ out){
    __shared__ float T[128][65];
    __shared__ float la[C2_], lc[C2_];
    int b = blockIdx.y, n0 = blockIdx.x * 64;
    int t = threadIdx.x;
    if (t < C2_){ la[t] = a2c2[t]; lc[t] = a2c2[C2_ + t]; }
    __syncthreads();
    int ck = t & 15, ng = t >> 4;
    #pragma unroll
    for (int g = 0; g < 4; ++g){
        int n = g*16 + ng;
        uint4 v = *(const uint4*)(z2bf + ((size_t)b*N_ + n0 + n)*C2_ + ck*8);
        float f[8]; EXT8(f, v);
        #pragma unroll
        for (int e = 0; e < 8; ++e){
            int ch = ck*8 + e;
            T[ch][n] = fmaxf(fmaf(la[ch], f[e], lc[ch]), 0.f);
        }
    }
    __syncthreads();
    #pragma unroll
    for (int g = 0; g < 8; ++g){
        int id = g*256 + t;
        int ch = id >> 4, f4 = id & 15;
        float4 o;
        o.x = T[ch][f4*4+0]; o.y = T[ch][f4*4+1];
        o.z = T[ch][f4*4+2]; o.w = T[ch][f4*4+3];
        *(float4*)(out + ((size_t)b*C2_ + ch)*N_ + n0 + f4*4) = o;
    }
}

extern "C" void kernel_launch(void* const* d_in, const int* in_sizes, int n_in,
                              void* d_out, int out_size, void* d_ws, size_t ws_size,
                              hipStream_t stream){
    const float* xyz1    = (const float*)d_in[0];
    const float* xyz2    = (const float*)d_in[1];
    const float* points1 = (const float*)d_in[2];
    const float* points2 = (const float*)d_in[3];
    const float* w1      = (const float*)d_in[4];
    const float* gamma1  = (const float*)d_in[6];
    const float* beta1   = (const float*)d_in[7];
    const float* w2      = (const float*)d_in[8];
    const float* gamma2  = (const float*)d_in[10];
    const float* beta2   = (const float*)d_in[11];
    float* outp = (float*)d_out;

    char* ws = (char*)d_ws;
    size_t off = 0;
    auto take = [&](size_t sz) -> void* {
        void* p = ws + off;
        off = (off + sz + 255) & ~(size_t)255;
        return p;
    };
    int4*   nn_idx4 = (int4*)  take((size_t)B_*N_*16);
    float4* nn_w4   = (float4*)take((size_t)B_*N_*16);
    u16*    w1bf    = (u16*)   take((size_t)C1_*CIN_*2);
    u16*    w2bf    = (u16*)   take((size_t)C2_*C1_*2);
    u16*    p2t     = (u16*)   take((size_t)B_*S_*D2_*2);
    u16*    y1      = (u16*)   take((size_t)B_*N_*C1_*2);
    u16*    z2bf    = (u16*)   take((size_t)B_*N_*C2_*2);
    float*  part1   = (float*) take((size_t)2*1024*C1_*4);
    float*  part2   = (float*) take((size_t)2*1024*C2_*4);
    float*  a1c1    = (float*) take((size_t)2*C1_*4);
    float*  a2c2    = (float*) take((size_t)2*C2_*4);

    hipLaunchKernelGGL(k_prep_w, dim3(384), dim3(256), 0, stream, w1, w2, w1bf, w2bf);
    hipLaunchKernelGGL(k_p2t, dim3(S_/32, D2_/32, B_), dim3(256), 0, stream, points2, p2t);
    hipLaunchKernelGGL(k_nn, dim3(N_/128, B_), dim3(256), 0, stream, xyz1, xyz2, nn_idx4, nn_w4);
    hipLaunchKernelGGL(k_conv1, dim3(N_/64, B_), dim3(256), 0, stream,
                       w1bf, points1, p2t, nn_idx4, nn_w4, y1, part1);
    hipLaunchKernelGGL(k_finalize, dim3(C1_), dim3(256), 0, stream,
                       part1, C1_, 1024, (float)(B_*N_), gamma1, beta1, a1c1);
    hipLaunchKernelGGL(k_conv2, dim3(N_/64, B_), dim3(256), 0, stream,
                       w2bf, y1, a1c1, z2bf, part2);
    hipLaunchKernelGGL(k_finalize, dim3(C2_), dim3(256), 0, stream,
                       part2, C2_, 1024, (float)(B_*N_), gamma2, beta2, a2c2);
    hipLaunchKernelGGL(k_apply, dim3(N_/64, B_), dim3(256), 0, stream, z2bf, a2c2, outp);
    (void)in_sizes; (void)n_in; (void)out_size; (void)ws_size; (void)d_in;
}

// Round 4
// 228.427 us; speedup vs baseline: 1.3132x; 1.1626x over previous
//
#include <hip/hip_runtime.h>
#include <stdint.h>

#define B_   8
#define N_   8192
#define S_   2048
#define D1_  128
#define D2_  256
#define CIN_ 384
#define C1_  256
#define C2_  128
#define NSUB_ 4

typedef uint16_t u16;
typedef uint32_t u32;
typedef __attribute__((ext_vector_type(8))) short bf16x8;
typedef __attribute__((ext_vector_type(4))) float f32x4;

static __device__ __forceinline__ u16 f2bf(float f){
    union { float f; u32 u; } v; v.f = f;
    u32 r = v.u + 0x7FFF + ((v.u >> 16) & 1);
    return (u16)(r >> 16);
}
static __device__ __forceinline__ float bf2f(u16 h){
    union { u32 u; float f; } v; v.u = ((u32)h) << 16;
    return v.f;
}
static __device__ __forceinline__ uint4 pack8(const u16 h[8]){
    uint4 u;
    u.x = (u32)h[0] | ((u32)h[1] << 16);
    u.y = (u32)h[2] | ((u32)h[3] << 16);
    u.z = (u32)h[4] | ((u32)h[5] << 16);
    u.w = (u32)h[6] | ((u32)h[7] << 16);
    return u;
}
#define EXT8(dst, u) { dst[0]=bf2f((u16)(u).x); dst[1]=bf2f((u16)((u).x>>16)); \
                       dst[2]=bf2f((u16)(u).y); dst[3]=bf2f((u16)((u).y>>16)); \
                       dst[4]=bf2f((u16)(u).z); dst[5]=bf2f((u16)((u).z>>16)); \
                       dst[6]=bf2f((u16)(u).w); dst[7]=bf2f((u16)((u).w>>16)); }

// ---------------- prep: weights -> bf16 ----------------
__global__ void k_prep_w(const float* __restrict__ w1, const float* __restrict__ w2,
                         u16* __restrict__ w1bf, u16* __restrict__ w2bf){
    int i = blockIdx.x * 256 + threadIdx.x;
    if (i < C1_*CIN_) w1bf[i] = f2bf(w1[i]);
    if (i < C2_*C1_)  w2bf[i] = f2bf(w2[i]);
}

// ---------------- prep: points2 [b][d][s] -> p2t bf16 [b][s][d] ----------------
__global__ __launch_bounds__(256) void k_p2t(const float* __restrict__ p2, u16* __restrict__ p2t){
    __shared__ float t[32][33];
    int b = blockIdx.z, s0 = blockIdx.x * 32, d0 = blockIdx.y * 32;
    int tt = threadIdx.x;
    int r = tt >> 3, c4 = (tt & 7) * 4;
    const float* src = p2 + (((size_t)b*D2_ + d0 + r) * S_ + s0 + c4);
    float4 v = *(const float4*)src;
    t[r][c4+0]=v.x; t[r][c4+1]=v.y; t[r][c4+2]=v.z; t[r][c4+3]=v.w;
    __syncthreads();
    ushort4 o;
    o.x = f2bf(t[c4+0][r]); o.y = f2bf(t[c4+1][r]);
    o.z = f2bf(t[c4+2][r]); o.w = f2bf(t[c4+3][r]);
    u16* dst = p2t + (((size_t)b*S_ + s0 + r) * D2_ + d0 + c4);
    *(ushort4*)dst = o;
}

// ---------------- 3-NN search: EXACT f32 compares (dual interleaved chains) ----------------
// NOTE (round-3 post-mortem): packed (dist&0xFFFFF800)|idx selection truncates the
// distance comparison and flips 3rd-vs-4th neighbor ordering for O(tens) of points
// vs the f32 reference -> absmax ~0.95. Selection must be exact-f32.
#define INS3G(dd, ss, D0,D1,D2,I0,I1,I2) do{ if ((dd) < D2){ if ((dd) < D1){ D2=D1; I2=I1; \
    if ((dd) < D0){ D1=D0; I1=I0; D0=(dd); I0=(ss); } else { D1=(dd); I1=(ss); } } \
    else { D2=(dd); I2=(ss); } } }while(0)

__global__ __launch_bounds__(256) void k_nn(const float* __restrict__ xyz1,
                                            const float* __restrict__ xyz2,
                                            int4* __restrict__ nn_idx4, float4* __restrict__ nn_w4){
    __shared__ float4 pt[S_];
    int b = blockIdx.y;
    int t = threadIdx.x;
    const float* xb = xyz2 + (size_t)b*3*S_;
    for (int i = t; i < S_; i += 256){
        float x = xb[i], y = xb[S_ + i], z = xb[2*S_ + i];
        pt[i] = make_float4(x, y, z, x*x + y*y + z*z);
    }
    __syncthreads();
    int nl = t >> 1, half = t & 1;
    int n = blockIdx.x * 128 + nl;
    const float* x1b = xyz1 + (size_t)b*3*N_;
    float px = x1b[n], py = x1b[N_ + n], pz = x1b[2*N_ + n];
    float n1 = px*px + py*py + pz*pz;
    float a0 = 3.4e38f, a1 = 3.4e38f, a2 = 3.4e38f;
    float b0 = 3.4e38f, b1v = 3.4e38f, b2v = 3.4e38f;
    int ia0 = 0, ia1 = 0, ia2 = 0, ib0 = 0, ib1 = 0, ib2 = 0;
    int sbeg = half * (S_/2), send = sbeg + (S_/2);
    #pragma unroll 4
    for (int s = sbeg; s < send; s += 2){
        float4 qa = pt[s];
        float4 qb = pt[s+1];
        float dota = fmaf(px, qa.x, fmaf(py, qa.y, pz*qa.z));
        float dotb = fmaf(px, qb.x, fmaf(py, qb.y, pz*qb.z));
        float da = fmaf(-2.f, dota, n1 + qa.w);
        float db = fmaf(-2.f, dotb, n1 + qb.w);
        INS3G(da, s,   a0,a1,a2, ia0,ia1,ia2);
        INS3G(db, s+1, b0,b1v,b2v, ib0,ib1,ib2);
    }
    INS3G(b0,  ib0, a0,a1,a2, ia0,ia1,ia2);
    INS3G(b1v, ib1, a0,a1,a2, ia0,ia1,ia2);
    INS3G(b2v, ib2, a0,a1,a2, ia0,ia1,ia2);
    float e0=__shfl_xor(a0,1), e1=__shfl_xor(a1,1), e2=__shfl_xor(a2,1);
    int   j0=__shfl_xor(ia0,1), j1=__shfl_xor(ia1,1), j2=__shfl_xor(ia2,1);
    INS3G(e0, j0, a0,a1,a2, ia0,ia1,ia2);
    INS3G(e1, j1, a0,a1,a2, ia0,ia1,ia2);
    INS3G(e2, j2, a0,a1,a2, ia0,ia1,ia2);
    if (half == 0){
        float r0 = 1.f/(a0+1e-8f), r1 = 1.f/(a1+1e-8f), r2 = 1.f/(a2+1e-8f);
        float inv = 1.f/(r0+r1+r2);
        size_t base = (size_t)b*N_ + n;
        nn_idx4[base] = make_int4(ia0, ia1, ia2, 0);
        nn_w4[base]   = make_float4(r0*inv, r1*inv, r2*inv, 0.f);
    }
}

// LDS swizzles: Xt row=768B, Zt row=512B
#define SWZ(nrow, kbyte)  ((((nrow)*768 + (kbyte))) ^ (((nrow)&7)<<4))
#define SWZ2(nrow, kbyte) ((((nrow)*512 + (kbyte))) ^ (((nrow)&7)<<4))

// ---------------- conv1: W-stationary, 8 waves, 256 points/block, 4 subtiles ----------------
__global__ __launch_bounds__(512, 2) void k_conv1(const u16* __restrict__ w1bf,
    const float* __restrict__ points1, const u16* __restrict__ p2t,
    const int4* __restrict__ nn_idx4, const float4* __restrict__ nn_w4,
    u16* __restrict__ y1, float* __restrict__ part1){
    __shared__ char sm[96*1024];
    int t = threadIdx.x;
    int wave = t >> 6, lane = t & 63;
    int b = blockIdx.y, n0g = blockIdx.x * 256;
    const int nlo = lane & 15, nhi = lane >> 4;

    // ---- W fragments persistent: wave owns out-ch [wave*32, wave*32+32)
    bf16x8 wfr[2][12];
    {
        const u16* wb = w1bf + ((size_t)(wave*32 + nlo))*CIN_ + nhi*8;
        #pragma unroll
        for (int mh = 0; mh < 2; ++mh)
            #pragma unroll
            for (int ks = 0; ks < 12; ++ks)
                wfr[mh][ks] = *(const bf16x8*)(wb + (size_t)mh*16*CIN_ + ks*32);
    }

    const int g8 = t & 15, pr = t >> 4;   // phase A roles: 8-ch group, row-pair
    const int rb = t >> 3, q8 = t & 7;    // phase B roles: row, 32-ch group

    float2 va2[8];
    uint4 uB[12];
    int4 nid; float4 nw;

    auto ISSUE_A = [&](int s){
        const float* pA = points1 + ((size_t)b*D1_ + g8*8)*N_ + n0g + s*64 + pr*2;
        #pragma unroll
        for (int j = 0; j < 8; ++j) va2[j] = *(const float2*)(pA + (size_t)j*N_);
        size_t nb = (size_t)b*N_ + n0g + s*64 + rb;
        nid = nn_idx4[nb]; nw = nn_w4[nb];
    };
    auto ISSUE_B = [&](){
        const u16* r0 = p2t + ((size_t)b*S_ + nid.x)*D2_ + q8*32;
        const u16* r1 = p2t + ((size_t)b*S_ + nid.y)*D2_ + q8*32;
        const u16* r2 = p2t + ((size_t)b*S_ + nid.z)*D2_ + q8*32;
        #pragma unroll
        for (int c = 0; c < 4; ++c){
            uB[c]   = *(const uint4*)(r0 + c*8);
            uB[4+c] = *(const uint4*)(r1 + c*8);
            uB[8+c] = *(const uint4*)(r2 + c*8);
        }
    };
    auto COMBINE = [&](char* X){
        #pragma unroll
        for (int e = 0; e < 2; ++e){
            u16 h[8];
            #pragma unroll
            for (int j = 0; j < 8; ++j) h[j] = f2bf(e ? va2[j].y : va2[j].x);
            *(uint4*)(X + SWZ(pr*2+e, g8*16)) = pack8(h);
        }
        #pragma unroll
        for (int c = 0; c < 4; ++c){
            float f0[8], f1[8], f2v[8];
            EXT8(f0, uB[c]); EXT8(f1, uB[4+c]); EXT8(f2v, uB[8+c]);
            u16 h[8];
            #pragma unroll
            for (int e = 0; e < 8; ++e)
                h[e] = f2bf(fmaf(nw.x, f0[e], fmaf(nw.y, f1[e], nw.z*f2v[e])));
            *(uint4*)(X + SWZ(rb, (128 + q8*32 + c*8)*2)) = pack8(h);
        }
    };

    char* Xc = sm;
    char* Xn = sm + 48*1024;

    ISSUE_A(0);
    ISSUE_B();
    COMBINE(Xc);
    __syncthreads();

    float s1a[2][4] = {{0,0,0,0},{0,0,0,0}}, s2a[2][4] = {{0,0,0,0},{0,0,0,0}};
    const int kgB = nhi*16;

    #pragma unroll 1
    for (int s = 0; s < NSUB_; ++s){
        if (s+1 < NSUB_) ISSUE_A(s+1);
        #pragma unroll
        for (int rowg = 0; rowg < 4; ++rowg){
            int nrow = rowg*16 + nlo;
            f32x4 acc0 = {0.f,0.f,0.f,0.f}, acc1 = {0.f,0.f,0.f,0.f};
            #pragma unroll
            for (int hf = 0; hf < 2; ++hf){
                bf16x8 xf[6];
                #pragma unroll
                for (int k6 = 0; k6 < 6; ++k6)
                    xf[k6] = *(const bf16x8*)(Xc + SWZ(nrow, (hf*6+k6)*64 + kgB));
                #pragma unroll
                for (int k6 = 0; k6 < 6; ++k6){
                    acc0 = __builtin_amdgcn_mfma_f32_16x16x32_bf16(wfr[0][hf*6+k6], xf[k6], acc0, 0,0,0);
                    acc1 = __builtin_amdgcn_mfma_f32_16x16x32_bf16(wfr[1][hf*6+k6], xf[k6], acc1, 0,0,0);
                }
            }
            if (s+1 < NSUB_ && rowg == 1) ISSUE_B();
            int n = n0g + s*64 + nrow;
            u16 h0[4], h1[4];
            #pragma unroll
            for (int r = 0; r < 4; ++r){
                h0[r] = f2bf(acc0[r]); h1[r] = f2bf(acc1[r]);
                s1a[0][r] += acc0[r]; s2a[0][r] += acc0[r]*acc0[r];
                s1a[1][r] += acc1[r]; s2a[1][r] += acc1[r]*acc1[r];
            }
            u16* yp = y1 + ((size_t)b*N_ + n)*C1_ + wave*32 + nhi*4;
            uint2 p0, p1;
            p0.x = (u32)h0[0] | ((u32)h0[1]<<16); p0.y = (u32)h0[2] | ((u32)h0[3]<<16);
            p1.x = (u32)h1[0] | ((u32)h1[1]<<16); p1.y = (u32)h1[2] | ((u32)h1[3]<<16);
            *(uint2*)yp = p0;
            *(uint2*)(yp + 16) = p1;
        }
        if (s+1 < NSUB_) COMBINE(Xn);
        __syncthreads();
        char* tmp = Xc; Xc = Xn; Xn = tmp;
    }

    // ---- BN1 partials: reduce over the 16-lane (n) group
    int blk = blockIdx.y * gridDim.x + blockIdx.x;
    #pragma unroll
    for (int mh = 0; mh < 2; ++mh)
        #pragma unroll
        for (int r = 0; r < 4; ++r){
            float a = s1a[mh][r], q = s2a[mh][r];
            #pragma unroll
            for (int m = 1; m <= 8; m <<= 1){ a += __shfl_xor(a, m); q += __shfl_xor(q, m); }
            if (nlo == 0){
                int ch = wave*32 + mh*16 + nhi*4 + r;
                part1[(size_t)blk*C1_ + ch] = a;
                part1[(size_t)256*C1_ + (size_t)blk*C1_ + ch] = q;
            }
        }
}

// ---------------- conv2: W-stationary, z = relu(bn1(y1)) on the fly ----------------
__global__ __launch_bounds__(512, 4) void k_conv2(const u16* __restrict__ w2bf,
    const u16* __restrict__ y1, const float* __restrict__ a1c1,
    u16* __restrict__ z2bf, float* __restrict__ part2){
    __shared__ char sm[64*1024];
    int t = threadIdx.x;
    int wave = t >> 6, lane = t & 63;
    int b = blockIdx.y, n0g = blockIdx.x * 256;
    const int nlo = lane & 15, nhi = lane >> 4;

    bf16x8 wfr[8];
    {
        const u16* wb = w2bf + ((size_t)(wave*16 + nlo))*C1_ + nhi*8;
        #pragma unroll
        for (int ks = 0; ks < 8; ++ks) wfr[ks] = *(const bf16x8*)(wb + ks*32);
    }

    const int r2 = t >> 4, q16 = t & 15;   // build roles: row-pair, 16-ch group
    float la8[16], lc8[16];
    {
        const float* ap = a1c1 + q16*16;
        #pragma unroll
        for (int c = 0; c < 4; ++c){
            *(float4*)(la8 + c*4) = *(const float4*)(ap + c*4);
            *(float4*)(lc8 + c*4) = *(const float4*)(ap + 256 + c*4);
        }
    }

    uint4 uy[4];
    auto ISSUE_Y = [&](int s){
        const u16* yp = y1 + ((size_t)b*N_ + n0g + s*64 + r2*2)*C1_ + q16*16;
        #pragma unroll
        for (int e = 0; e < 2; ++e)
            #pragma unroll
            for (int c = 0; c < 2; ++c)
                uy[e*2+c] = *(const uint4*)(yp + (size_t)e*C1_ + c*8);
    };
    auto COMBINE = [&](char* Z){
        #pragma unroll
        for (int e = 0; e < 2; ++e)
            #pragma unroll
            for (int c = 0; c < 2; ++c){
                float f[8]; EXT8(f, uy[e*2+c]);
                u16 h[8];
                #pragma unroll
                for (int k = 0; k < 8; ++k){
                    float z = fmaf(la8[c*8+k], f[k], lc8[c*8+k]);
                    h[k] = f2bf(z > 0.f ? z : 0.f);
                }
                *(uint4*)(Z + SWZ2(r2*2+e, q16*32 + c*16)) = pack8(h);
            }
    };

    char* Zc = sm;
    char* Zn = sm + 32*1024;

    ISSUE_Y(0);
    COMBINE(Zc);
    __syncthreads();

    float s1a[4] = {0,0,0,0}, s2a[4] = {0,0,0,0};
    const int kgB = nhi*16;

    #pragma unroll 1
    for (int s = 0; s < NSUB_; ++s){
        if (s+1 < NSUB_) ISSUE_Y(s+1);
        #pragma unroll
        for (int rowg = 0; rowg < 4; ++rowg){
            int nrow = rowg*16 + nlo;
            f32x4 acc = {0.f,0.f,0.f,0.f};
            #pragma unroll
            for (int hf = 0; hf < 2; ++hf){
                bf16x8 xf[4];
                #pragma unroll
                for (int k4 = 0; k4 < 4; ++k4)
                    xf[k4] = *(const bf16x8*)(Zc + SWZ2(nrow, (hf*4+k4)*64 + kgB));
                #pragma unroll
                for (int k4 = 0; k4 < 4; ++k4)
                    acc = __builtin_amdgcn_mfma_f32_16x16x32_bf16(wfr[hf*4+k4], xf[k4], acc, 0,0,0);
            }
            int n = n0g + s*64 + nrow;
            u16 h[4];
            #pragma unroll
            for (int r = 0; r < 4; ++r){
                h[r] = f2bf(acc[r]);
                s1a[r] += acc[r]; s2a[r] += acc[r]*acc[r];
            }
            uint2 p;
            p.x = (u32)h[0] | ((u32)h[1]<<16); p.y = (u32)h[2] | ((u32)h[3]<<16);
            *(uint2*)(z2bf + ((size_t)b*N_ + n)*C2_ + wave*16 + nhi*4) = p;
        }
        if (s+1 < NSUB_) COMBINE(Zn);
        __syncthreads();
        char* tmp = Zc; Zc = Zn; Zn = tmp;
    }

    int blk = blockIdx.y * gridDim.x + blockIdx.x;
    #pragma unroll
    for (int r = 0; r < 4; ++r){
        float a = s1a[r], q = s2a[r];
        #pragma unroll
        for (int m = 1; m <= 8; m <<= 1){ a += __shfl_xor(a, m); q += __shfl_xor(q, m); }
        if (nlo == 0){
            int ch = wave*16 + nhi*4 + r;
            part2[(size_t)blk*C2_ + ch] = a;
            part2[(size_t)256*C2_ + (size_t)blk*C2_ + ch] = q;
        }
    }
}

// ---------------- finalize BN stats ----------------
__global__ void k_finalize(const float* __restrict__ part, int C, int NB, float count,
                           const float* __restrict__ gamma, const float* __restrict__ beta,
                           float* __restrict__ ac){
    int o = blockIdx.x, t = threadIdx.x;
    float s1 = 0.f, s2 = 0.f;
    for (int i = t; i < NB; i += 256){
        s1 += part[(size_t)i*C + o];
        s2 += part[(size_t)NB*C + (size_t)i*C + o];
    }
    #pragma unroll
    for (int m = 1; m < 64; m <<= 1){ s1 += __shfl_xor(s1, m); s2 += __shfl_xor(s2, m); }
    __shared__ float ls[8];
    int wave = t >> 6, lane = t & 63;
    if (lane == 0){ ls[wave] = s1; ls[4+wave] = s2; }
    __syncthreads();
    if (t == 0){
        s1 = ls[0]+ls[1]+ls[2]+ls[3];
        s2 = ls[4]+ls[5]+ls[6]+ls[7];
        float mean = s1 / count;
        float var  = s2 / count - mean*mean;
        float inv  = rsqrtf(var + 1e-5f);
        float a = gamma[o] * inv;
        ac[o] = a;
        ac[C + o] = beta[o] - mean*a;
    }
}

// ---------------- apply BN2+ReLU with transpose: z2bf [b][n][ch] -> out [b][ch][n] f32 ----------------
__global__ __launch_bounds__(256) void k_apply(const u16* __restrict__ z2bf,
                                               const float* __restrict__ a2c2,
                                               float* __restrict__ out){
    __shared__ float T[128][65];
    __shared__ float la[C2_], lc[C2_];
    int b = blockIdx.y, n0 = blockIdx.x * 64;
    int t = threadIdx.x;
    if (t < C2_){ la[t] = a2c2[t]; lc[t] = a2c2[C2_ + t]; }
    __syncthreads();
    int ck = t & 15, ng = t >> 4;
    #pragma unroll
    for (int g = 0; g < 4; ++g){
        int n = g*16 + ng;
        uint4 v = *(const uint4*)(z2bf + ((size_t)b*N_ + n0 + n)*C2_ + ck*8);
        float f[8]; EXT8(f, v);
        #pragma unroll
        for (int e = 0; e < 8; ++e){
            int ch = ck*8 + e;
            T[ch][n] = fmaxf(fmaf(la[ch], f[e], lc[ch]), 0.f);
        }
    }
    __syncthreads();
    #pragma unroll
    for (int g = 0; g < 8; ++g){
        int id = g*256 + t;
        int ch = id >> 4, f4 = id & 15;
        float4 o;
        o.x = T[ch][f4*4+0]; o.y = T[ch][f4*4+1];
        o.z = T[ch][f4*4+2]; o.w = T[ch][f4*4+3];
        *(float4*)(out + ((size_t)b*C2_ + ch)*N_ + n0 + f4*4) = o;
    }
}

extern "C" void kernel_launch(void* const* d_in, const int* in_sizes, int n_in,
                              void* d_out, int out_size, void* d_ws, size_t ws_size,
                              hipStream_t stream){
    const float* xyz1    = (const float*)d_in[0];
    const float* xyz2    = (const float*)d_in[1];
    const float* points1 = (const float*)d_in[2];
    const float* points2 = (const float*)d_in[3];
    const float* w1      = (const float*)d_in[4];
    const float* gamma1  = (const float*)d_in[6];
    const float* beta1   = (const float*)d_in[7];
    const float* w2      = (const float*)d_in[8];
    const float* gamma2  = (const float*)d_in[10];
    const float* beta2   = (const float*)d_in[11];
    float* outp = (float*)d_out;

    char* ws = (char*)d_ws;
    size_t off = 0;
    auto take = [&](size_t sz) -> void* {
        void* p = ws + off;
        off = (off + sz + 255) & ~(size_t)255;
        return p;
    };
    int4*   nn_idx4 = (int4*)  take((size_t)B_*N_*16);
    float4* nn_w4   = (float4*)take((size_t)B_*N_*16);
    u16*    w1bf    = (u16*)   take((size_t)C1_*CIN_*2);
    u16*    w2bf    = (u16*)   take((size_t)C2_*C1_*2);
    u16*    p2t     = (u16*)   take((size_t)B_*S_*D2_*2);
    u16*    y1      = (u16*)   take((size_t)B_*N_*C1_*2);
    u16*    z2bf    = (u16*)   take((size_t)B_*N_*C2_*2);
    float*  part1   = (float*) take((size_t)2*256*C1_*4);
    float*  part2   = (float*) take((size_t)2*256*C2_*4);
    float*  a1c1    = (float*) take((size_t)2*C1_*4);
    float*  a2c2    = (float*) take((size_t)2*C2_*4);

    hipLaunchKernelGGL(k_prep_w, dim3(384), dim3(256), 0, stream, w1, w2, w1bf, w2bf);
    hipLaunchKernelGGL(k_p2t, dim3(S_/32, D2_/32, B_), dim3(256), 0, stream, points2, p2t);
    hipLaunchKernelGGL(k_nn, dim3(N_/128, B_), dim3(256), 0, stream, xyz1, xyz2, nn_idx4, nn_w4);
    hipLaunchKernelGGL(k_conv1, dim3(N_/256, B_), dim3(512), 0, stream,
                       w1bf, points1, p2t, nn_idx4, nn_w4, y1, part1);
    hipLaunchKernelGGL(k_finalize, dim3(C1_), dim3(256), 0, stream,
                       part1, C1_, 256, (float)(B_*N_), gamma1, beta1, a1c1);
    hipLaunchKernelGGL(k_conv2, dim3(N_/256, B_), dim3(512), 0, stream,
                       w2bf, y1, a1c1, z2bf, part2);
    hipLaunchKernelGGL(k_finalize, dim3(C2_), dim3(256), 0, stream,
                       part2, C2_, 256, (float)(B_*N_), gamma2, beta2, a2c2);
    hipLaunchKernelGGL(k_apply, dim3(N_/64, B_), dim3(256), 0, stream, z2bf, a2c2, outp);
    (void)in_sizes; (void)n_in; (void)out_size; (void)ws_size; (void)d_in;
}

// Round 5
// 200.800 us; speedup vs baseline: 1.4939x; 1.1376x over previous
//
#include <hip/hip_runtime.h>
#include <stdint.h>

#define B_   8
#define N_   8192
#define S_   2048
#define D1_  128
#define D2_  256
#define CIN_ 384
#define C1_  256
#define C2_  128
#define NSUB_ 4

typedef uint16_t u16;
typedef uint32_t u32;
typedef __attribute__((ext_vector_type(8))) short bf16x8;
typedef __attribute__((ext_vector_type(4))) float f32x4;

static __device__ __forceinline__ u16 f2bf(float f){
    union { float f; u32 u; } v; v.f = f;
    u32 r = v.u + 0x7FFF + ((v.u >> 16) & 1);
    return (u16)(r >> 16);
}
static __device__ __forceinline__ float bf2f(u16 h){
    union { u32 u; float f; } v; v.u = ((u32)h) << 16;
    return v.f;
}
static __device__ __forceinline__ uint4 pack8(const u16 h[8]){
    uint4 u;
    u.x = (u32)h[0] | ((u32)h[1] << 16);
    u.y = (u32)h[2] | ((u32)h[3] << 16);
    u.z = (u32)h[4] | ((u32)h[5] << 16);
    u.w = (u32)h[6] | ((u32)h[7] << 16);
    return u;
}
#define EXT8(dst, u) { dst[0]=bf2f((u16)(u).x); dst[1]=bf2f((u16)((u).x>>16)); \
                       dst[2]=bf2f((u16)(u).y); dst[3]=bf2f((u16)((u).y>>16)); \
                       dst[4]=bf2f((u16)(u).z); dst[5]=bf2f((u16)((u).z>>16)); \
                       dst[6]=bf2f((u16)(u).w); dst[7]=bf2f((u16)((u).w>>16)); }

// ---------------- prep: weights -> bf16 ----------------
__global__ void k_prep_w(const float* __restrict__ w1, const float* __restrict__ w2,
                         u16* __restrict__ w1bf, u16* __restrict__ w2bf){
    int i = blockIdx.x * 256 + threadIdx.x;
    if (i < C1_*CIN_) w1bf[i] = f2bf(w1[i]);
    if (i < C2_*C1_)  w2bf[i] = f2bf(w2[i]);
}

// ---------------- prep: points2 [b][d][s] -> p2t bf16 [b][s][d] ----------------
__global__ __launch_bounds__(256) void k_p2t(const float* __restrict__ p2, u16* __restrict__ p2t){
    __shared__ float t[32][33];
    int b = blockIdx.z, s0 = blockIdx.x * 32, d0 = blockIdx.y * 32;
    int tt = threadIdx.x;
    int r = tt >> 3, c4 = (tt & 7) * 4;
    const float* src = p2 + (((size_t)b*D2_ + d0 + r) * S_ + s0 + c4);
    float4 v = *(const float4*)src;
    t[r][c4+0]=v.x; t[r][c4+1]=v.y; t[r][c4+2]=v.z; t[r][c4+3]=v.w;
    __syncthreads();
    ushort4 o;
    o.x = f2bf(t[c4+0][r]); o.y = f2bf(t[c4+1][r]);
    o.z = f2bf(t[c4+2][r]); o.w = f2bf(t[c4+3][r]);
    u16* dst = p2t + (((size_t)b*S_ + s0 + r) * D2_ + d0 + c4);
    *(ushort4*)dst = o;
}

// ---------------- 3-NN search: 4 threads/query, staggered conflict-free scan ----------------
// Selection arithmetic kept bit-identical to the passing version (round-3 lesson:
// any truncation of the distance compare flips 3rd/4th neighbors -> fails).
#define INS3G(dd, ss, D0,D1,D2,I0,I1,I2) do{ if ((dd) < D2){ if ((dd) < D1){ D2=D1; I2=I1; \
    if ((dd) < D0){ D1=D0; I1=I0; D0=(dd); I0=(ss); } else { D1=(dd); I1=(ss); } } \
    else { D2=(dd); I2=(ss); } } }while(0)

__global__ __launch_bounds__(256) void k_nn(const float* __restrict__ xyz1,
                                            const float* __restrict__ xyz2,
                                            int4* __restrict__ nn_idx4, float4* __restrict__ nn_w4){
    __shared__ float4 pt[S_];
    int b = blockIdx.y;
    int t = threadIdx.x;
    const float* xb = xyz2 + (size_t)b*3*S_;
    for (int i = t; i < S_; i += 256){
        float x = xb[i], y = xb[S_ + i], z = xb[2*S_ + i];
        pt[i] = make_float4(x, y, z, x*x + y*y + z*z);
    }
    __syncthreads();
    int nl = t >> 2, q = t & 3;              // 64 queries/block, 4 threads each
    int n = blockIdx.x * 64 + nl;
    const float* x1b = xyz1 + (size_t)b*3*N_;
    float px = x1b[n], py = x1b[N_ + n], pz = x1b[2*N_ + n];
    float n1 = px*px + py*py + pz*pz;
    float a0 = 3.4e38f, a1 = 3.4e38f, a2 = 3.4e38f;
    float b0 = 3.4e38f, b1v = 3.4e38f, b2v = 3.4e38f;
    int ia0 = 0, ia1 = 0, ia2 = 0, ib0 = 0, ib1 = 0, ib2 = 0;
    // quarter q scans s = q*512 + ((j + 2q) & 511): bank quad = (4j + 8q) mod 32,
    // disjoint across q for both interleaved chains -> zero LDS bank conflicts.
    const int sbase = q * 512, rot = q * 2;
    #pragma unroll 4
    for (int j = 0; j < 512; j += 2){
        int s0 = sbase + ((j + rot) & 511);
        int s1 = sbase + ((j + 1 + rot) & 511);
        float4 qa = pt[s0];
        float4 qb = pt[s1];
        float dota = fmaf(px, qa.x, fmaf(py, qa.y, pz*qa.z));
        float dotb = fmaf(px, qb.x, fmaf(py, qb.y, pz*qb.z));
        float da = fmaf(-2.f, dota, n1 + qa.w);
        float db = fmaf(-2.f, dotb, n1 + qb.w);
        INS3G(da, s0, a0,a1,a2, ia0,ia1,ia2);
        INS3G(db, s1, b0,b1v,b2v, ib0,ib1,ib2);
    }
    INS3G(b0,  ib0, a0,a1,a2, ia0,ia1,ia2);
    INS3G(b1v, ib1, a0,a1,a2, ia0,ia1,ia2);
    INS3G(b2v, ib2, a0,a1,a2, ia0,ia1,ia2);
    #pragma unroll
    for (int m = 1; m <= 2; m <<= 1){
        float e0=__shfl_xor(a0,m), e1=__shfl_xor(a1,m), e2=__shfl_xor(a2,m);
        int   j0=__shfl_xor(ia0,m), j1=__shfl_xor(ia1,m), j2=__shfl_xor(ia2,m);
        INS3G(e0, j0, a0,a1,a2, ia0,ia1,ia2);
        INS3G(e1, j1, a0,a1,a2, ia0,ia1,ia2);
        INS3G(e2, j2, a0,a1,a2, ia0,ia1,ia2);
    }
    if (q == 0){
        float r0 = 1.f/(a0+1e-8f), r1 = 1.f/(a1+1e-8f), r2 = 1.f/(a2+1e-8f);
        float inv = 1.f/(r0+r1+r2);
        size_t base = (size_t)b*N_ + n;
        nn_idx4[base] = make_int4(ia0, ia1, ia2, 0);
        nn_w4[base]   = make_float4(r0*inv, r1*inv, r2*inv, 0.f);
    }
}

// LDS swizzles: Xt row=768B, Zt row=512B
#define SWZ(nrow, kbyte)  ((((nrow)*768 + (kbyte))) ^ (((nrow)&7)<<4))
#define SWZ2(nrow, kbyte) ((((nrow)*512 + (kbyte))) ^ (((nrow)&7)<<4))

// ---------------- conv1: W-stationary, 8 waves, 256 points/block, 4 subtiles ----------------
__global__ __launch_bounds__(512, 2) void k_conv1(const u16* __restrict__ w1bf,
    const float* __restrict__ points1, const u16* __restrict__ p2t,
    const int4* __restrict__ nn_idx4, const float4* __restrict__ nn_w4,
    u16* __restrict__ y1, float* __restrict__ part1){
    __shared__ char sm[96*1024];
    int t = threadIdx.x;
    int wave = t >> 6, lane = t & 63;
    int b = blockIdx.y, n0g = blockIdx.x * 256;
    const int nlo = lane & 15, nhi = lane >> 4;

    // ---- W fragments persistent: wave owns out-ch [wave*32, wave*32+32)
    bf16x8 wfr[2][12];
    {
        const u16* wb = w1bf + ((size_t)(wave*32 + nlo))*CIN_ + nhi*8;
        #pragma unroll
        for (int mh = 0; mh < 2; ++mh)
            #pragma unroll
            for (int ks = 0; ks < 12; ++ks)
                wfr[mh][ks] = *(const bf16x8*)(wb + (size_t)mh*16*CIN_ + ks*32);
    }

    const int g8 = t & 15, pr = t >> 4;   // phase A roles: 8-ch group, row-pair
    const int rb = t >> 3, q8 = t & 7;    // phase B roles: row, 32-ch group

    float2 va2[8];
    uint4 uB[12];
    int4 nid; float4 nw;

    auto ISSUE_A = [&](int s){
        const float* pA = points1 + ((size_t)b*D1_ + g8*8)*N_ + n0g + s*64 + pr*2;
        #pragma unroll
        for (int j = 0; j < 8; ++j) va2[j] = *(const float2*)(pA + (size_t)j*N_);
        size_t nb = (size_t)b*N_ + n0g + s*64 + rb;
        nid = nn_idx4[nb]; nw = nn_w4[nb];
    };
    auto ISSUE_B = [&](){
        const u16* r0 = p2t + ((size_t)b*S_ + nid.x)*D2_ + q8*32;
        const u16* r1 = p2t + ((size_t)b*S_ + nid.y)*D2_ + q8*32;
        const u16* r2 = p2t + ((size_t)b*S_ + nid.z)*D2_ + q8*32;
        #pragma unroll
        for (int c = 0; c < 4; ++c){
            uB[c]   = *(const uint4*)(r0 + c*8);
            uB[4+c] = *(const uint4*)(r1 + c*8);
            uB[8+c] = *(const uint4*)(r2 + c*8);
        }
    };
    auto COMBINE = [&](char* X){
        #pragma unroll
        for (int e = 0; e < 2; ++e){
            u16 h[8];
            #pragma unroll
            for (int j = 0; j < 8; ++j) h[j] = f2bf(e ? va2[j].y : va2[j].x);
            *(uint4*)(X + SWZ(pr*2+e, g8*16)) = pack8(h);
        }
        #pragma unroll
        for (int c = 0; c < 4; ++c){
            float f0[8], f1[8], f2v[8];
            EXT8(f0, uB[c]); EXT8(f1, uB[4+c]); EXT8(f2v, uB[8+c]);
            u16 h[8];
            #pragma unroll
            for (int e = 0; e < 8; ++e)
                h[e] = f2bf(fmaf(nw.x, f0[e], fmaf(nw.y, f1[e], nw.z*f2v[e])));
            *(uint4*)(X + SWZ(rb, (128 + q8*32 + c*8)*2)) = pack8(h);
        }
    };

    char* Xc = sm;
    char* Xn = sm + 48*1024;

    ISSUE_A(0);
    ISSUE_B();
    COMBINE(Xc);
    __syncthreads();

    float s1a[2][4] = {{0,0,0,0},{0,0,0,0}}, s2a[2][4] = {{0,0,0,0},{0,0,0,0}};
    const int kgB = nhi*16;

    #pragma unroll 1
    for (int s = 0; s < NSUB_; ++s){
        if (s+1 < NSUB_) ISSUE_A(s+1);
        #pragma unroll
        for (int rowg = 0; rowg < 4; ++rowg){
            int nrow = rowg*16 + nlo;
            f32x4 acc0 = {0.f,0.f,0.f,0.f}, acc1 = {0.f,0.f,0.f,0.f};
            #pragma unroll
            for (int hf = 0; hf < 2; ++hf){
                bf16x8 xf[6];
                #pragma unroll
                for (int k6 = 0; k6 < 6; ++k6)
                    xf[k6] = *(const bf16x8*)(Xc + SWZ(nrow, (hf*6+k6)*64 + kgB));
                #pragma unroll
                for (int k6 = 0; k6 < 6; ++k6){
                    acc0 = __builtin_amdgcn_mfma_f32_16x16x32_bf16(wfr[0][hf*6+k6], xf[k6], acc0, 0,0,0);
                    acc1 = __builtin_amdgcn_mfma_f32_16x16x32_bf16(wfr[1][hf*6+k6], xf[k6], acc1, 0,0,0);
                }
            }
            if (s+1 < NSUB_ && rowg == 1) ISSUE_B();
            int n = n0g + s*64 + nrow;
            u16 h0[4], h1[4];
            #pragma unroll
            for (int r = 0; r < 4; ++r){
                h0[r] = f2bf(acc0[r]); h1[r] = f2bf(acc1[r]);
                s1a[0][r] += acc0[r]; s2a[0][r] += acc0[r]*acc0[r];
                s1a[1][r] += acc1[r]; s2a[1][r] += acc1[r]*acc1[r];
            }
            u16* yp = y1 + ((size_t)b*N_ + n)*C1_ + wave*32 + nhi*4;
            uint2 p0, p1;
            p0.x = (u32)h0[0] | ((u32)h0[1]<<16); p0.y = (u32)h0[2] | ((u32)h0[3]<<16);
            p1.x = (u32)h1[0] | ((u32)h1[1]<<16); p1.y = (u32)h1[2] | ((u32)h1[3]<<16);
            *(uint2*)yp = p0;
            *(uint2*)(yp + 16) = p1;
        }
        if (s+1 < NSUB_) COMBINE(Xn);
        __syncthreads();
        char* tmp = Xc; Xc = Xn; Xn = tmp;
    }

    // ---- BN1 partials: reduce over the 16-lane (n) group
    int blk = blockIdx.y * gridDim.x + blockIdx.x;
    #pragma unroll
    for (int mh = 0; mh < 2; ++mh)
        #pragma unroll
        for (int r = 0; r < 4; ++r){
            float a = s1a[mh][r], qv = s2a[mh][r];
            #pragma unroll
            for (int m = 1; m <= 8; m <<= 1){ a += __shfl_xor(a, m); qv += __shfl_xor(qv, m); }
            if (nlo == 0){
                int ch = wave*32 + mh*16 + nhi*4 + r;
                part1[(size_t)blk*C1_ + ch] = a;
                part1[(size_t)256*C1_ + (size_t)blk*C1_ + ch] = qv;
            }
        }
}

// ---------------- conv2: W-stationary, z = relu(bn1(y1)) on the fly ----------------
__global__ __launch_bounds__(512, 4) void k_conv2(const u16* __restrict__ w2bf,
    const u16* __restrict__ y1, const float* __restrict__ a1c1,
    u16* __restrict__ z2bf, float* __restrict__ part2){
    __shared__ char sm[64*1024];
    int t = threadIdx.x;
    int wave = t >> 6, lane = t & 63;
    int b = blockIdx.y, n0g = blockIdx.x * 256;
    const int nlo = lane & 15, nhi = lane >> 4;

    bf16x8 wfr[8];
    {
        const u16* wb = w2bf + ((size_t)(wave*16 + nlo))*C1_ + nhi*8;
        #pragma unroll
        for (int ks = 0; ks < 8; ++ks) wfr[ks] = *(const bf16x8*)(wb + ks*32);
    }

    const int r2 = t >> 4, q16 = t & 15;   // build roles: row-pair, 16-ch group
    float la8[16], lc8[16];
    {
        const float* ap = a1c1 + q16*16;
        #pragma unroll
        for (int c = 0; c < 4; ++c){
            *(float4*)(la8 + c*4) = *(const float4*)(ap + c*4);
            *(float4*)(lc8 + c*4) = *(const float4*)(ap + 256 + c*4);
        }
    }

    uint4 uy[4];
    auto ISSUE_Y = [&](int s){
        const u16* yp = y1 + ((size_t)b*N_ + n0g + s*64 + r2*2)*C1_ + q16*16;
        #pragma unroll
        for (int e = 0; e < 2; ++e)
            #pragma unroll
            for (int c = 0; c < 2; ++c)
                uy[e*2+c] = *(const uint4*)(yp + (size_t)e*C1_ + c*8);
    };
    auto COMBINE = [&](char* Z){
        #pragma unroll
        for (int e = 0; e < 2; ++e)
            #pragma unroll
            for (int c = 0; c < 2; ++c){
                float f[8]; EXT8(f, uy[e*2+c]);
                u16 h[8];
                #pragma unroll
                for (int k = 0; k < 8; ++k){
                    float z = fmaf(la8[c*8+k], f[k], lc8[c*8+k]);
                    h[k] = f2bf(z > 0.f ? z : 0.f);
                }
                *(uint4*)(Z + SWZ2(r2*2+e, q16*32 + c*16)) = pack8(h);
            }
    };

    char* Zc = sm;
    char* Zn = sm + 32*1024;

    ISSUE_Y(0);
    COMBINE(Zc);
    __syncthreads();

    float s1a[4] = {0,0,0,0}, s2a[4] = {0,0,0,0};
    const int kgB = nhi*16;

    #pragma unroll 1
    for (int s = 0; s < NSUB_; ++s){
        if (s+1 < NSUB_) ISSUE_Y(s+1);
        #pragma unroll
        for (int rowg = 0; rowg < 4; ++rowg){
            int nrow = rowg*16 + nlo;
            f32x4 acc = {0.f,0.f,0.f,0.f};
            #pragma unroll
            for (int hf = 0; hf < 2; ++hf){
                bf16x8 xf[4];
                #pragma unroll
                for (int k4 = 0; k4 < 4; ++k4)
                    xf[k4] = *(const bf16x8*)(Zc + SWZ2(nrow, (hf*4+k4)*64 + kgB));
                #pragma unroll
                for (int k4 = 0; k4 < 4; ++k4)
                    acc = __builtin_amdgcn_mfma_f32_16x16x32_bf16(wfr[hf*4+k4], xf[k4], acc, 0,0,0);
            }
            int n = n0g + s*64 + nrow;
            u16 h[4];
            #pragma unroll
            for (int r = 0; r < 4; ++r){
                h[r] = f2bf(acc[r]);
                s1a[r] += acc[r]; s2a[r] += acc[r]*acc[r];
            }
            uint2 p;
            p.x = (u32)h[0] | ((u32)h[1]<<16); p.y = (u32)h[2] | ((u32)h[3]<<16);
            *(uint2*)(z2bf + ((size_t)b*N_ + n)*C2_ + wave*16 + nhi*4) = p;
        }
        if (s+1 < NSUB_) COMBINE(Zn);
        __syncthreads();
        char* tmp = Zc; Zc = Zn; Zn = tmp;
    }

    int blk = blockIdx.y * gridDim.x + blockIdx.x;
    #pragma unroll
    for (int r = 0; r < 4; ++r){
        float a = s1a[r], qv = s2a[r];
        #pragma unroll
        for (int m = 1; m <= 8; m <<= 1){ a += __shfl_xor(a, m); qv += __shfl_xor(qv, m); }
        if (nlo == 0){
            int ch = wave*16 + nhi*4 + r;
            part2[(size_t)blk*C2_ + ch] = a;
            part2[(size_t)256*C2_ + (size_t)blk*C2_ + ch] = qv;
        }
    }
}

// ---------------- finalize BN stats ----------------
__global__ void k_finalize(const float* __restrict__ part, int C, int NB, float count,
                           const float* __restrict__ gamma, const float* __restrict__ beta,
                           float* __restrict__ ac){
    int o = blockIdx.x, t = threadIdx.x;
    float s1 = 0.f, s2 = 0.f;
    for (int i = t; i < NB; i += 256){
        s1 += part[(size_t)i*C + o];
        s2 += part[(size_t)NB*C + (size_t)i*C + o];
    }
    #pragma unroll
    for (int m = 1; m < 64; m <<= 1){ s1 += __shfl_xor(s1, m); s2 += __shfl_xor(s2, m); }
    __shared__ float ls[8];
    int wave = t >> 6, lane = t & 63;
    if (lane == 0){ ls[wave] = s1; ls[4+wave] = s2; }
    __syncthreads();
    if (t == 0){
        s1 = ls[0]+ls[1]+ls[2]+ls[3];
        s2 = ls[4]+ls[5]+ls[6]+ls[7];
        float mean = s1 / count;
        float var  = s2 / count - mean*mean;
        float inv  = rsqrtf(var + 1e-5f);
        float a = gamma[o] * inv;
        ac[o] = a;
        ac[C + o] = beta[o] - mean*a;
    }
}

// ---------------- apply BN2+ReLU with transpose: z2bf [b][n][ch] -> out [b][ch][n] f32 ----------------
__global__ __launch_bounds__(256) void k_apply(const u16* __restrict__ z2bf,
                                               const float* __restrict__ a2c2,
                                               float* __restrict__ out){
    __shared__ float T[128][65];
    __shared__ float la[C2_], lc[C2_];
    int b = blockIdx.y, n0 = blockIdx.x * 64;
    int t = threadIdx.x;
    if (t < C2_){ la[t] = a2c2[t]; lc[t] = a2c2[C2_ + t]; }
    __syncthreads();
    int ck = t & 15, ng = t >> 4;
    #pragma unroll
    for (int g = 0; g < 4; ++g){
        int n = g*16 + ng;
        uint4 v = *(const uint4*)(z2bf + ((size_t)b*N_ + n0 + n)*C2_ + ck*8);
        float f[8]; EXT8(f, v);
        #pragma unroll
        for (int e = 0; e < 8; ++e){
            int ch = ck*8 + e;
            T[ch][n] = fmaxf(fmaf(la[ch], f[e], lc[ch]), 0.f);
        }
    }
    __syncthreads();
    #pragma unroll
    for (int g = 0; g < 8; ++g){
        int id = g*256 + t;
        int ch = id >> 4, f4 = id & 15;
        float4 o;
        o.x = T[ch][f4*4+0]; o.y = T[ch][f4*4+1];
        o.z = T[ch][f4*4+2]; o.w = T[ch][f4*4+3];
        *(float4*)(out + ((size_t)b*C2_ + ch)*N_ + n0 + f4*4) = o;
    }
}

extern "C" void kernel_launch(void* const* d_in, const int* in_sizes, int n_in,
                              void* d_out, int out_size, void* d_ws, size_t ws_size,
                              hipStream_t stream){
    const float* xyz1    = (const float*)d_in[0];
    const float* xyz2    = (const float*)d_in[1];
    const float* points1 = (const float*)d_in[2];
    const float* points2 = (const float*)d_in[3];
    const float* w1      = (const float*)d_in[4];
    const float* gamma1  = (const float*)d_in[6];
    const float* beta1   = (const float*)d_in[7];
    const float* w2      = (const float*)d_in[8];
    const float* gamma2  = (const float*)d_in[10];
    const float* beta2   = (const float*)d_in[11];
    float* outp = (float*)d_out;

    char* ws = (char*)d_ws;
    size_t off = 0;
    auto take = [&](size_t sz) -> void* {
        void* p = ws + off;
        off = (off + sz + 255) & ~(size_t)255;
        return p;
    };
    int4*   nn_idx4 = (int4*)  take((size_t)B_*N_*16);
    float4* nn_w4   = (float4*)take((size_t)B_*N_*16);
    u16*    w1bf    = (u16*)   take((size_t)C1_*CIN_*2);
    u16*    w2bf    = (u16*)   take((size_t)C2_*C1_*2);
    u16*    p2t     = (u16*)   take((size_t)B_*S_*D2_*2);
    u16*    y1      = (u16*)   take((size_t)B_*N_*C1_*2);
    u16*    z2bf    = (u16*)   take((size_t)B_*N_*C2_*2);
    float*  part1   = (float*) take((size_t)2*256*C1_*4);
    float*  part2   = (float*) take((size_t)2*256*C2_*4);
    float*  a1c1    = (float*) take((size_t)2*C1_*4);
    float*  a2c2    = (float*) take((size_t)2*C2_*4);

    hipLaunchKernelGGL(k_prep_w, dim3(384), dim3(256), 0, stream, w1, w2, w1bf, w2bf);
    hipLaunchKernelGGL(k_p2t, dim3(S_/32, D2_/32, B_), dim3(256), 0, stream, points2, p2t);
    hipLaunchKernelGGL(k_nn, dim3(N_/64, B_), dim3(256), 0, stream, xyz1, xyz2, nn_idx4, nn_w4);
    hipLaunchKernelGGL(k_conv1, dim3(N_/256, B_), dim3(512), 0, stream,
                       w1bf, points1, p2t, nn_idx4, nn_w4, y1, part1);
    hipLaunchKernelGGL(k_finalize, dim3(C1_), dim3(256), 0, stream,
                       part1, C1_, 256, (float)(B_*N_), gamma1, beta1, a1c1);
    hipLaunchKernelGGL(k_conv2, dim3(N_/256, B_), dim3(512), 0, stream,
                       w2bf, y1, a1c1, z2bf, part2);
    hipLaunchKernelGGL(k_finalize, dim3(C2_), dim3(256), 0, stream,
                       part2, C2_, 256, (float)(B_*N_), gamma2, beta2, a2c2);
    hipLaunchKernelGGL(k_apply, dim3(N_/64, B_), dim3(256), 0, stream, z2bf, a2c2, outp);
    (void)in_sizes; (void)n_in; (void)out_size; (void)ws_size; (void)d_in;
}